// Round 13
// baseline (110.494 us; speedup 1.0000x reference)
//
#include <hip/hip_runtime.h>

// Sizes (fixed by the problem)
#define NB 16
#define NQ 128
#define NK 512
#define NH 128
#define NDV 128

#define KPAD 132  // 128+4 floats: b128 lane*KPAD reads measured 0 conflicts

typedef __attribute__((ext_vector_type(8))) short short8;
typedef __attribute__((ext_vector_type(4))) float f32x4;
typedef __attribute__((ext_vector_type(2))) float f32x2;

#define C2LOG2E 2.8853900817779268f  // 2*log2(e): folded into proj epilogue
#define LOG2E   1.4426950408889634f

__device__ __forceinline__ short f2bf(float x) {   // RNE f32 -> bf16
    unsigned u = __float_as_uint(x);
    unsigned r = (u + 0x7fffu + ((u >> 16) & 1u)) >> 16;
    return (short)r;
}
__device__ __forceinline__ float bf2f(short s) {
    return __uint_as_float(((unsigned)(unsigned short)s) << 16);
}

// ---------------------------------------------------------------------------
// Kernel 1: pack W into MFMA B-fragment order, split bf16 hi/lo. (round-10)
// ---------------------------------------------------------------------------
__global__ __launch_bounds__(256) void wsplit_kernel(
    const float* __restrict__ Wq, const float* __restrict__ Wk,
    const float* __restrict__ wv,
    short* __restrict__ pqh, short* __restrict__ pql,
    short* __restrict__ pkh, short* __restrict__ pkl,
    float* __restrict__ w2)
{
    int blk = blockIdx.x;          // 16 blocks = w(2) x ht(8)
    int t   = threadIdx.x;         // ks(4) x lane(64)
    if (blk == 0 && t < NH) w2[t] = 2.0f * wv[t];
    int w = blk >> 3, ht = blk & 7;
    int ks = t >> 6, lane = t & 63;
    int m = lane & 15, quad = lane >> 4;
    const float* W = w ? Wk : Wq;
    short* ph = w ? pkh : pqh;
    short* pl = w ? pkl : pql;
    short8 hi, lo;
#pragma unroll
    for (int j = 0; j < 8; ++j) {
        float x = W[(size_t)(ks * 32 + quad * 8 + j) * NH + ht * 16 + m];
        short h = f2bf(x);
        hi[j] = h;
        lo[j] = f2bf(x - bf2f(h));
    }
    size_t o = (size_t)((ht * 4 + ks) * 64 + lane) * 8;
    *(short8*)(ph + o) = hi;
    *(short8*)(pl + o) = lo;
}

// ---------------------------------------------------------------------------
// Kernel 2: projection + exp. (round-10 exact)
// ---------------------------------------------------------------------------
__global__ __launch_bounds__(256) void proj_kernel(
    const float* __restrict__ Xq, const float* __restrict__ Xk,
    const short* __restrict__ pqh, const short* __restrict__ pql,
    const short* __restrict__ pkh, const short* __restrict__ pkl,
    float* __restrict__ Eq, float* __restrict__ Ek)
{
    __shared__ float s_x[16 * KPAD];     // 8448 B

    int blk = blockIdx.x;
    const float* X; const short* ph; const short* pl; float* Y; int row0;
    if (blk < 128) { X = Xq; ph = pqh; pl = pql; Y = Eq; row0 = blk * 16; }
    else           { X = Xk; ph = pkh; pl = pkl; Y = Ek; row0 = (blk - 128) * 16; }
    int t = threadIdx.x;
    int wave = t >> 6, lane = t & 63;
    int m = lane & 15, quad = lane >> 4;

#pragma unroll
    for (int r = 0; r < 2; ++r) {
        int i = (t + r * 256) * 4;
        int row = i >> 7, col = i & 127;
        *(f32x4*)&s_x[row * KPAD + col] =
            *(const f32x4*)&X[(size_t)(row0 + row) * NH + col];
    }
    __syncthreads();

    short8 AH[4], AL[4];
#pragma unroll
    for (int ks = 0; ks < 4; ++ks) {
        int base = m * KPAD + ks * 32 + quad * 8;
        f32x4 x0 = *(const f32x4*)&s_x[base];
        f32x4 x1 = *(const f32x4*)&s_x[base + 4];
#pragma unroll
        for (int j = 0; j < 4; ++j) {
            short h0 = f2bf(x0[j]);
            AH[ks][j] = h0; AL[ks][j] = f2bf(x0[j] - bf2f(h0));
            short h1 = f2bf(x1[j]);
            AH[ks][j + 4] = h1; AL[ks][j + 4] = f2bf(x1[j] - bf2f(h1));
        }
    }
#pragma unroll
    for (int hi = 0; hi < 2; ++hi) {
        int ht = wave * 2 + hi;
        f32x4 acc = {0.f, 0.f, 0.f, 0.f};
#pragma unroll
        for (int ks = 0; ks < 4; ++ks) {
            size_t o = (size_t)((ht * 4 + ks) * 64 + lane) * 8;
            short8 bh = *(const short8*)(ph + o);
            short8 bl = *(const short8*)(pl + o);
            acc = __builtin_amdgcn_mfma_f32_16x16x32_bf16(AH[ks], bl, acc, 0, 0, 0);
            acc = __builtin_amdgcn_mfma_f32_16x16x32_bf16(AL[ks], bh, acc, 0, 0, 0);
            acc = __builtin_amdgcn_mfma_f32_16x16x32_bf16(AH[ks], bh, acc, 0, 0, 0);
        }
        // D: col = lane&15, row = quad*4 + r  [verified layout]
#pragma unroll
        for (int r = 0; r < 4; ++r)
            Y[(size_t)(row0 + quad * 4 + r) * NH + ht * 16 + m] =
                __builtin_amdgcn_exp2f(acc[r] * C2LOG2E);
    }
}

// ---------------------------------------------------------------------------
// Kernel 3 v3: scores. Grid = b*64 + qt*8 + kc (1024 blocks x 256 thr):
// b in HIGH bits so each batch's 64 blocks hit 64 distinct CUs and each CU's
// ~4 blocks come from 4 DIFFERENT batches (old b=blk&15 guaranteed each CU's
// two blocks were the SAME batch -> heavy batch ran 2 serial full blocks;
// measured insensitive to inner shape at 17.7 us -> imbalance-bound).
// Chunk = 16q x 64k; LDS 42.5 KB -> 3 blocks/CU. Wave = q-group (4q),
// lane = one k. Inner = round-8's proven 8-chain shape.
// ---------------------------------------------------------------------------
__global__ __launch_bounds__(256) void score_kernel(
    const float* __restrict__ Eqp, const float* __restrict__ Ekp,
    const int* __restrict__ vlen, const float* __restrict__ w2,
    float* __restrict__ P)
{
    __shared__ float s_ek[64 * KPAD];    // 33792 B
    __shared__ float s_eq[16 * NH];      //  8192 B
    __shared__ float s_w2[NH];           //   512 B

    int blk = blockIdx.x;
    int b    = blk >> 6;                 // batch in HIGH bits
    int rest = blk & 63;
    int qt = rest >> 3, kc = rest & 7;   // qt 0..7 (16q), kc 0..7 (64k)
    int q0 = qt * 16, k0 = kc * 64;
    int t  = threadIdx.x;

    int nv = vlen[b];
    nv = max(1, min(NK, nv));
    float* Pb = P + ((size_t)b * NQ + q0) * NK;

    if (k0 >= nv) {
        // fully masked chunk: 16q x 64k = 256 f32x4, one per thread
        int q = t >> 4, kk = (t & 15) * 4;
        f32x4 z = {0.f, 0.f, 0.f, 0.f};
        *(f32x4*)&Pb[(size_t)q * NK + k0 + kk] = z;
        return;
    }

    // stage Ek chunk (64 rows), Eq tile, w2
    for (int i = t; i < 64 * 32; i += 256) {
        int row = i >> 5, c4 = i & 31;
        *(f32x4*)&s_ek[row * KPAD + c4 * 4] =
            *(const f32x4*)&Ekp[((size_t)b * NK + k0 + row) * NH + c4 * 4];
    }
#pragma unroll
    for (int r = 0; r < 2; ++r) {
        int i = t + r * 256;
        *(f32x4*)&s_eq[i * 4] =
            *(const f32x4*)&Eqp[((size_t)b * NQ + q0) * NH + i * 4];
    }
    if (t < 32) *(f32x4*)&s_w2[t * 4] = *(const f32x4*)&w2[t * 4];
    __syncthreads();

    int lane = t & 63, g = t >> 6;       // wave = q-group g (4 q's)

    // Wsum = sum_h wv = 0.5 * sum_h w2
    float s2 = s_w2[lane] + s_w2[lane + 64];
#pragma unroll
    for (int off = 32; off; off >>= 1) s2 += __shfl_xor(s2, off);
    float wsum = 0.5f * s2;

    const float* ek = &s_ek[lane * KPAD];
    const float* q0p = &s_eq[(g * 4 + 0) * NH];
    const float* q1p = &s_eq[(g * 4 + 1) * NH];
    const float* q2p = &s_eq[(g * 4 + 2) * NH];
    const float* q3p = &s_eq[(g * 4 + 3) * NH];

    float c00 = 0.f, c01 = 0.f, c10 = 0.f, c11 = 0.f;
    float c20 = 0.f, c21 = 0.f, c30 = 0.f, c31 = 0.f;
#pragma unroll
    for (int hh = 0; hh < NH; hh += 8) {
        f32x4 kA = *(const f32x4*)(ek + hh);
        f32x4 kB = *(const f32x4*)(ek + hh + 4);
        f32x4 wA = *(const f32x4*)(s_w2 + hh);
        f32x4 wB = *(const f32x4*)(s_w2 + hh + 4);
        f32x4 qA0 = *(const f32x4*)(q0p + hh), qB0 = *(const f32x4*)(q0p + hh + 4);
        f32x4 qA1 = *(const f32x4*)(q1p + hh), qB1 = *(const f32x4*)(q1p + hh + 4);
        f32x4 qA2 = *(const f32x4*)(q2p + hh), qB2 = *(const f32x4*)(q2p + hh + 4);
        f32x4 qA3 = *(const f32x4*)(q3p + hh), qB3 = *(const f32x4*)(q3p + hh + 4);
#pragma unroll
        for (int i = 0; i < 4; ++i) {
            c00 = fmaf(wA[i], __builtin_amdgcn_rcpf(fmaf(qA0[i], kA[i], 1.0f)), c00);
            c10 = fmaf(wA[i], __builtin_amdgcn_rcpf(fmaf(qA1[i], kA[i], 1.0f)), c10);
            c20 = fmaf(wA[i], __builtin_amdgcn_rcpf(fmaf(qA2[i], kA[i], 1.0f)), c20);
            c30 = fmaf(wA[i], __builtin_amdgcn_rcpf(fmaf(qA3[i], kA[i], 1.0f)), c30);
            c01 = fmaf(wB[i], __builtin_amdgcn_rcpf(fmaf(qB0[i], kB[i], 1.0f)), c01);
            c11 = fmaf(wB[i], __builtin_amdgcn_rcpf(fmaf(qB1[i], kB[i], 1.0f)), c11);
            c21 = fmaf(wB[i], __builtin_amdgcn_rcpf(fmaf(qB2[i], kB[i], 1.0f)), c21);
            c31 = fmaf(wB[i], __builtin_amdgcn_rcpf(fmaf(qB3[i], kB[i], 1.0f)), c31);
        }
    }
    int kg = k0 + lane;
    bool valid = kg < nv;
    float p0 = valid ? __builtin_amdgcn_exp2f((wsum - (c00 + c01)) * LOG2E) : 0.f;
    float p1 = valid ? __builtin_amdgcn_exp2f((wsum - (c10 + c11)) * LOG2E) : 0.f;
    float p2 = valid ? __builtin_amdgcn_exp2f((wsum - (c20 + c21)) * LOG2E) : 0.f;
    float p3 = valid ? __builtin_amdgcn_exp2f((wsum - (c30 + c31)) * LOG2E) : 0.f;
    float* Pr = Pb + (size_t)(g * 4) * NK + kg;
    Pr[0 * NK] = p0;                     // coalesced dword stores per q-row
    Pr[1 * NK] = p1;
    Pr[2 * NK] = p2;
    Pr[3 * NK] = p3;
}

// ---------------------------------------------------------------------------
// Kernel 4: normalize + AV. (round-10 inner; b decoded from HIGH bits so a
// heavy batch's 16 blocks land on 16 distinct CUs)
// ---------------------------------------------------------------------------
__global__ __launch_bounds__(256) void av_kernel(
    const float* __restrict__ P, const float* __restrict__ V,
    const int* __restrict__ vlen, float* __restrict__ out)
{
    __shared__ float s_p[8 * NK];        // 16 KB

    int blk = blockIdx.x;
    int b = blk >> 4, qt = blk & 15;     // b HIGH bits; qt 0..15 (8 q each)
    int q0 = qt * 8;
    int t = threadIdx.x;

    int nv = vlen[b];
    nv = max(1, min(NK, nv));
    int nv8 = (nv + 7) & ~7;

    const f32x4* Pv = (const f32x4*)(P + ((size_t)b * NQ + q0) * NK);
#pragma unroll
    for (int r = 0; r < 4; ++r)
        ((f32x4*)s_p)[t + r * 256] = Pv[t + r * 256];
    __syncthreads();

    int lane = t & 63, w = t >> 6;
    int qa = w * 2, qb = qa + 1;
    const float* pa = &s_p[qa * NK];
    const float* pb = &s_p[qb * NK];

    // row sums (zeros beyond nv included -> exact)
    f32x4 sa0 = *(const f32x4*)(pa + lane * 8);
    f32x4 sa1 = *(const f32x4*)(pa + lane * 8 + 4);
    f32x4 sb0 = *(const f32x4*)(pb + lane * 8);
    f32x4 sb1 = *(const f32x4*)(pb + lane * 8 + 4);
    float sa = ((sa0[0] + sa0[1]) + (sa0[2] + sa0[3])) +
               ((sa1[0] + sa1[1]) + (sa1[2] + sa1[3]));
    float sb = ((sb0[0] + sb0[1]) + (sb0[2] + sb0[3])) +
               ((sb1[0] + sb1[1]) + (sb1[2] + sb1[3]));
#pragma unroll
    for (int off = 32; off; off >>= 1) {
        sa += __shfl_xor(sa, off);
        sb += __shfl_xor(sb, off);
    }
    float ra = 1.0f / sa, rb = 1.0f / sb;

    int par = lane >> 5;                 // k parity for this half-wave
    int dl  = lane & 31;
    int dv0 = dl * 4;                    // 4 dv per lane (f32x4)
    const float* Vb = V + (size_t)b * NK * NDV + dv0;
    f32x4 Oa = {0.f, 0.f, 0.f, 0.f};
    f32x4 Ob = {0.f, 0.f, 0.f, 0.f};
    for (int k = 0; k < nv8; k += 8) {
        f32x4 pA0 = *(const f32x4*)(pa + k);         // LDS broadcasts
        f32x4 pA1 = *(const f32x4*)(pa + k + 4);
        f32x4 pB0 = *(const f32x4*)(pb + k);
        f32x4 pB1 = *(const f32x4*)(pb + k + 4);
        f32x4 v0 = *(const f32x4*)(Vb + (size_t)(k + 0 + par) * NDV);
        f32x4 v1 = *(const f32x4*)(Vb + (size_t)(k + 2 + par) * NDV);
        f32x4 v2 = *(const f32x4*)(Vb + (size_t)(k + 4 + par) * NDV);
        f32x4 v3 = *(const f32x4*)(Vb + (size_t)(k + 6 + par) * NDV);
        float a0 = pA0[par], a1 = pA0[2 + par], a2 = pA1[par], a3 = pA1[2 + par];
        float b0 = pB0[par], b1 = pB0[2 + par], b2 = pB1[par], b3 = pB1[2 + par];
#pragma unroll
        for (int j = 0; j < 4; ++j) {
            Oa[j] = fmaf(a0, v0[j], Oa[j]); Ob[j] = fmaf(b0, v0[j], Ob[j]);
            Oa[j] = fmaf(a1, v1[j], Oa[j]); Ob[j] = fmaf(b1, v1[j], Ob[j]);
            Oa[j] = fmaf(a2, v2[j], Oa[j]); Ob[j] = fmaf(b2, v2[j], Ob[j]);
            Oa[j] = fmaf(a3, v3[j], Oa[j]); Ob[j] = fmaf(b3, v3[j], Ob[j]);
        }
    }
    // combine even/odd partial sums across the half-waves
#pragma unroll
    for (int j = 0; j < 4; ++j) {
        Oa[j] += __shfl_xor(Oa[j], 32);
        Ob[j] += __shfl_xor(Ob[j], 32);
    }
    // half 0 stores row qa, half 1 stores row qb (each covers all 128 dv)
    if (par == 0) {
        f32x4 o = {Oa[0] * ra, Oa[1] * ra, Oa[2] * ra, Oa[3] * ra};
        *(f32x4*)&out[((size_t)b * NQ + q0 + qa) * NDV + dv0] = o;
    } else {
        f32x4 o = {Ob[0] * rb, Ob[1] * rb, Ob[2] * rb, Ob[3] * rb};
        *(f32x4*)&out[((size_t)b * NQ + q0 + qb) * NDV + dv0] = o;
    }
}

extern "C" void kernel_launch(void* const* d_in, const int* in_sizes, int n_in,
                              void* d_out, int out_size, void* d_ws, size_t ws_size,
                              hipStream_t stream) {
    const float* q  = (const float*)d_in[0];  // (16,128,128) f32
    const float* ks = (const float*)d_in[1];  // (16,512,128) f32
    const float* vs = (const float*)d_in[2];  // (16,512,128) f32
    const int*   vl = (const int*)d_in[3];    // (16,) i32
    const float* wq = (const float*)d_in[4];  // (128,128) f32
    const float* wk = (const float*)d_in[5];  // (128,128) f32
    const float* wv = (const float*)d_in[6];  // (128,) f32

    // ws layout (~9.3 MB)
    float* Eq = (float*)d_ws;                     // 2048*128
    float* Ek = Eq + 2048 * 128;                  // 8192*128
    float* P  = Ek + (size_t)8192 * 128;          // 16*128*512
    float* w2 = P + (size_t)NB * NQ * NK;         // 128
    short* pqh = (short*)(w2 + 128);              // 4 x 16384 bf16 frags
    short* pql = pqh + 16384;
    short* pkh = pql + 16384;
    short* pkl = pkh + 16384;

    wsplit_kernel<<<16, 256, 0, stream>>>(wq, wk, wv, pqh, pql, pkh, pkl, w2);
    proj_kernel<<<640, 256, 0, stream>>>(q, ks, pqh, pql, pkh, pkl, Eq, Ek);
    score_kernel<<<1024, 256, 0, stream>>>(Eq, Ek, vl, w2, P);
    av_kernel<<<256, 256, 0, stream>>>(P, vs, vl, (float*)d_out);
}

// Round 14
// 107.137 us; speedup vs baseline: 1.0313x; 1.0313x over previous
//
#include <hip/hip_runtime.h>

// Sizes (fixed by the problem)
#define NB 16
#define NQ 128
#define NK 512
#define NH 128
#define NDV 128

#define KPAD 132  // 128+4 floats: b128 lane*KPAD reads measured 0 conflicts

typedef __attribute__((ext_vector_type(8))) short short8;
typedef __attribute__((ext_vector_type(4))) float f32x4;
typedef __attribute__((ext_vector_type(2))) float f32x2;

#define C2LOG2E 2.8853900817779268f  // 2*log2(e): folded into proj epilogue
#define LOG2E   1.4426950408889634f

__device__ __forceinline__ short f2bf(float x) {   // RNE f32 -> bf16
    unsigned u = __float_as_uint(x);
    unsigned r = (u + 0x7fffu + ((u >> 16) & 1u)) >> 16;
    return (short)r;
}
__device__ __forceinline__ float bf2f(short s) {
    return __uint_as_float(((unsigned)(unsigned short)s) << 16);
}

// ---------------------------------------------------------------------------
// Kernel 1: pack W into MFMA B-fragment order, split bf16 hi/lo. (round-10)
// ---------------------------------------------------------------------------
__global__ __launch_bounds__(256) void wsplit_kernel(
    const float* __restrict__ Wq, const float* __restrict__ Wk,
    const float* __restrict__ wv,
    short* __restrict__ pqh, short* __restrict__ pql,
    short* __restrict__ pkh, short* __restrict__ pkl,
    float* __restrict__ w2)
{
    int blk = blockIdx.x;          // 16 blocks = w(2) x ht(8)
    int t   = threadIdx.x;         // ks(4) x lane(64)
    if (blk == 0 && t < NH) w2[t] = 2.0f * wv[t];
    int w = blk >> 3, ht = blk & 7;
    int ks = t >> 6, lane = t & 63;
    int m = lane & 15, quad = lane >> 4;
    const float* W = w ? Wk : Wq;
    short* ph = w ? pkh : pqh;
    short* pl = w ? pkl : pql;
    short8 hi, lo;
#pragma unroll
    for (int j = 0; j < 8; ++j) {
        float x = W[(size_t)(ks * 32 + quad * 8 + j) * NH + ht * 16 + m];
        short h = f2bf(x);
        hi[j] = h;
        lo[j] = f2bf(x - bf2f(h));
    }
    size_t o = (size_t)((ht * 4 + ks) * 64 + lane) * 8;
    *(short8*)(ph + o) = hi;
    *(short8*)(pl + o) = lo;
}

// ---------------------------------------------------------------------------
// Kernel 2: projection + exp. (round-10 exact)
// ---------------------------------------------------------------------------
__global__ __launch_bounds__(256) void proj_kernel(
    const float* __restrict__ Xq, const float* __restrict__ Xk,
    const short* __restrict__ pqh, const short* __restrict__ pql,
    const short* __restrict__ pkh, const short* __restrict__ pkl,
    float* __restrict__ Eq, float* __restrict__ Ek)
{
    __shared__ float s_x[16 * KPAD];     // 8448 B

    int blk = blockIdx.x;
    const float* X; const short* ph; const short* pl; float* Y; int row0;
    if (blk < 128) { X = Xq; ph = pqh; pl = pql; Y = Eq; row0 = blk * 16; }
    else           { X = Xk; ph = pkh; pl = pkl; Y = Ek; row0 = (blk - 128) * 16; }
    int t = threadIdx.x;
    int wave = t >> 6, lane = t & 63;
    int m = lane & 15, quad = lane >> 4;

#pragma unroll
    for (int r = 0; r < 2; ++r) {
        int i = (t + r * 256) * 4;
        int row = i >> 7, col = i & 127;
        *(f32x4*)&s_x[row * KPAD + col] =
            *(const f32x4*)&X[(size_t)(row0 + row) * NH + col];
    }
    __syncthreads();

    short8 AH[4], AL[4];
#pragma unroll
    for (int ks = 0; ks < 4; ++ks) {
        int base = m * KPAD + ks * 32 + quad * 8;
        f32x4 x0 = *(const f32x4*)&s_x[base];
        f32x4 x1 = *(const f32x4*)&s_x[base + 4];
#pragma unroll
        for (int j = 0; j < 4; ++j) {
            short h0 = f2bf(x0[j]);
            AH[ks][j] = h0; AL[ks][j] = f2bf(x0[j] - bf2f(h0));
            short h1 = f2bf(x1[j]);
            AH[ks][j + 4] = h1; AL[ks][j + 4] = f2bf(x1[j] - bf2f(h1));
        }
    }
#pragma unroll
    for (int hi = 0; hi < 2; ++hi) {
        int ht = wave * 2 + hi;
        f32x4 acc = {0.f, 0.f, 0.f, 0.f};
#pragma unroll
        for (int ks = 0; ks < 4; ++ks) {
            size_t o = (size_t)((ht * 4 + ks) * 64 + lane) * 8;
            short8 bh = *(const short8*)(ph + o);
            short8 bl = *(const short8*)(pl + o);
            acc = __builtin_amdgcn_mfma_f32_16x16x32_bf16(AH[ks], bl, acc, 0, 0, 0);
            acc = __builtin_amdgcn_mfma_f32_16x16x32_bf16(AL[ks], bh, acc, 0, 0, 0);
            acc = __builtin_amdgcn_mfma_f32_16x16x32_bf16(AH[ks], bh, acc, 0, 0, 0);
        }
        // D: col = lane&15, row = quad*4 + r  [verified layout]
#pragma unroll
        for (int r = 0; r < 4; ++r)
            Y[(size_t)(row0 + quad * 4 + r) * NH + ht * 16 + m] =
                __builtin_amdgcn_exp2f(acc[r] * C2LOG2E);
    }
}

// ---------------------------------------------------------------------------
// Kernel 3: scores. Round-10 shape EXACTLY (512 blocks x 512 thr, b=blk&15,
// 16q x 128k chunks, wave=4q, lane=one k) — only change: pair-reciprocal,
// 2 rcp -> 1 rcp + 3 mul. Single-variable test of the rcp-throughput theory
// (score measured 17.7us incl gap, insensitive to LDS shape & balance).
// ---------------------------------------------------------------------------
__global__ __launch_bounds__(512) void score_kernel(
    const float* __restrict__ Eqp, const float* __restrict__ Ekp,
    const int* __restrict__ vlen, const float* __restrict__ w2,
    float* __restrict__ P)
{
    __shared__ float s_ek[128 * KPAD];   // 67584 B
    __shared__ float s_eq[16 * NH];      //  8192 B
    __shared__ float s_w2[NH];           //   512 B

    int blk = blockIdx.x;
    int b    = blk & 15;                 // batch-interleaved
    int rest = blk >> 4;
    int qt = rest & 7, kc = rest >> 3;   // qt 0..7 (16q each), kc 0..3 (128k)
    int q0 = qt * 16, k0 = kc * 128;
    int t  = threadIdx.x;

    int nv = vlen[b];
    nv = max(1, min(NK, nv));
    float* Pb = P + ((size_t)b * NQ + q0) * NK;

    if (k0 >= nv) {
        // fully masked chunk: 16q x 128k = 2048 floats = one f32x4/thread
        int q = t >> 5, kk = (t & 31) * 4;
        f32x4 z = {0.f, 0.f, 0.f, 0.f};
        *(f32x4*)&Pb[(size_t)q * NK + k0 + kk] = z;
        return;
    }

    for (int i = t; i < 128 * 32; i += 512) {
        int row = i >> 5, c4 = i & 31;
        *(f32x4*)&s_ek[row * KPAD + c4 * 4] =
            *(const f32x4*)&Ekp[((size_t)b * NK + k0 + row) * NH + c4 * 4];
    }
    *(f32x4*)&s_eq[t * 4] =
        *(const f32x4*)&Eqp[((size_t)b * NQ + q0) * NH + t * 4];
    if (t < 32) *(f32x4*)&s_w2[t * 4] = *(const f32x4*)&w2[t * 4];
    __syncthreads();

    int lane = t & 63, w = t >> 6;
    int g = w & 3, hf = w >> 2;

    // Wsum = sum_h wv = 0.5 * sum_h w2
    float s2 = s_w2[lane] + s_w2[lane + 64];
#pragma unroll
    for (int off = 32; off; off >>= 1) s2 += __shfl_xor(s2, off);
    float wsum = 0.5f * s2;

    const float* ek = &s_ek[(hf * 64 + lane) * KPAD];
    const float* e0 = &s_eq[(g * 4 + 0) * NH];
    const float* e1 = &s_eq[(g * 4 + 1) * NH];
    const float* e2 = &s_eq[(g * 4 + 2) * NH];
    const float* e3 = &s_eq[(g * 4 + 3) * NH];

    float c00 = 0.f, c01 = 0.f, c10 = 0.f, c11 = 0.f;
    float c20 = 0.f, c21 = 0.f, c30 = 0.f, c31 = 0.f;

    // acc0 += wa/(qa*ka+1); acc1 += wb/(qb*kb+1) with ONE rcp.
    // x in (1, 4e8], x1*x2 <= 1.6e17 (normal), R >= 6e-18 (normal); ~2 ulp.
#define PAIR(acc0, acc1, qa, ka, wa, qb, kb, wb)                        \
    {                                                                   \
        float x1 = fmaf(qa, ka, 1.0f);                                  \
        float x2 = fmaf(qb, kb, 1.0f);                                  \
        float R = __builtin_amdgcn_rcpf(x1 * x2);                       \
        acc0 = fmaf(wa, R * x2, acc0);                                  \
        acc1 = fmaf(wb, R * x1, acc1);                                  \
    }

#pragma unroll
    for (int hh = 0; hh < NH; hh += 8) {
        f32x4 kA = *(const f32x4*)(ek + hh);
        f32x4 kB = *(const f32x4*)(ek + hh + 4);
        f32x4 wA = *(const f32x4*)(s_w2 + hh);
        f32x4 wB = *(const f32x4*)(s_w2 + hh + 4);
        f32x4 qA0 = *(const f32x4*)(e0 + hh), qB0 = *(const f32x4*)(e0 + hh + 4);
        f32x4 qA1 = *(const f32x4*)(e1 + hh), qB1 = *(const f32x4*)(e1 + hh + 4);
        f32x4 qA2 = *(const f32x4*)(e2 + hh), qB2 = *(const f32x4*)(e2 + hh + 4);
        f32x4 qA3 = *(const f32x4*)(e3 + hh), qB3 = *(const f32x4*)(e3 + hh + 4);
#pragma unroll
        for (int i = 0; i < 4; ++i) {
            PAIR(c00, c01, qA0[i], kA[i], wA[i], qB0[i], kB[i], wB[i]);
            PAIR(c10, c11, qA1[i], kA[i], wA[i], qB1[i], kB[i], wB[i]);
            PAIR(c20, c21, qA2[i], kA[i], wA[i], qB2[i], kB[i], wB[i]);
            PAIR(c30, c31, qA3[i], kA[i], wA[i], qB3[i], kB[i], wB[i]);
        }
    }
#undef PAIR
    int kg = k0 + hf * 64 + lane;
    bool valid = kg < nv;
    float p0 = valid ? __builtin_amdgcn_exp2f((wsum - (c00 + c01)) * LOG2E) : 0.f;
    float p1 = valid ? __builtin_amdgcn_exp2f((wsum - (c10 + c11)) * LOG2E) : 0.f;
    float p2 = valid ? __builtin_amdgcn_exp2f((wsum - (c20 + c21)) * LOG2E) : 0.f;
    float p3 = valid ? __builtin_amdgcn_exp2f((wsum - (c30 + c31)) * LOG2E) : 0.f;
    float* Pr = Pb + (size_t)(g * 4) * NK + kg;
    Pr[0 * NK] = p0;                     // coalesced dword stores per q-row
    Pr[1 * NK] = p1;
    Pr[2 * NK] = p2;
    Pr[3 * NK] = p3;
}

// ---------------------------------------------------------------------------
// Kernel 4: normalize + AV. (round-10 exact)
// ---------------------------------------------------------------------------
__global__ __launch_bounds__(256) void av_kernel(
    const float* __restrict__ P, const float* __restrict__ V,
    const int* __restrict__ vlen, float* __restrict__ out)
{
    __shared__ float s_p[8 * NK];        // 16 KB

    int blk = blockIdx.x;
    int b = blk & 15, qt = blk >> 4;     // qt 0..15 (8 q each)
    int q0 = qt * 8;
    int t = threadIdx.x;

    int nv = vlen[b];
    nv = max(1, min(NK, nv));
    int nv8 = (nv + 7) & ~7;

    const f32x4* Pv = (const f32x4*)(P + ((size_t)b * NQ + q0) * NK);
#pragma unroll
    for (int r = 0; r < 4; ++r)
        ((f32x4*)s_p)[t + r * 256] = Pv[t + r * 256];
    __syncthreads();

    int lane = t & 63, w = t >> 6;
    int qa = w * 2, qb = qa + 1;
    const float* pa = &s_p[qa * NK];
    const float* pb = &s_p[qb * NK];

    // row sums (zeros beyond nv included -> exact)
    f32x4 sa0 = *(const f32x4*)(pa + lane * 8);
    f32x4 sa1 = *(const f32x4*)(pa + lane * 8 + 4);
    f32x4 sb0 = *(const f32x4*)(pb + lane * 8);
    f32x4 sb1 = *(const f32x4*)(pb + lane * 8 + 4);
    float sa = ((sa0[0] + sa0[1]) + (sa0[2] + sa0[3])) +
               ((sa1[0] + sa1[1]) + (sa1[2] + sa1[3]));
    float sb = ((sb0[0] + sb0[1]) + (sb0[2] + sb0[3])) +
               ((sb1[0] + sb1[1]) + (sb1[2] + sb1[3]));
#pragma unroll
    for (int off = 32; off; off >>= 1) {
        sa += __shfl_xor(sa, off);
        sb += __shfl_xor(sb, off);
    }
    float ra = 1.0f / sa, rb = 1.0f / sb;

    int par = lane >> 5;                 // k parity for this half-wave
    int dl  = lane & 31;
    int dv0 = dl * 4;                    // 4 dv per lane (f32x4)
    const float* Vb = V + (size_t)b * NK * NDV + dv0;
    f32x4 Oa = {0.f, 0.f, 0.f, 0.f};
    f32x4 Ob = {0.f, 0.f, 0.f, 0.f};
    for (int k = 0; k < nv8; k += 8) {
        f32x4 pA0 = *(const f32x4*)(pa + k);         // LDS broadcasts
        f32x4 pA1 = *(const f32x4*)(pa + k + 4);
        f32x4 pB0 = *(const f32x4*)(pb + k);
        f32x4 pB1 = *(const f32x4*)(pb + k + 4);
        f32x4 v0 = *(const f32x4*)(Vb + (size_t)(k + 0 + par) * NDV);
        f32x4 v1 = *(const f32x4*)(Vb + (size_t)(k + 2 + par) * NDV);
        f32x4 v2 = *(const f32x4*)(Vb + (size_t)(k + 4 + par) * NDV);
        f32x4 v3 = *(const f32x4*)(Vb + (size_t)(k + 6 + par) * NDV);
        float a0 = pA0[par], a1 = pA0[2 + par], a2 = pA1[par], a3 = pA1[2 + par];
        float b0 = pB0[par], b1 = pB0[2 + par], b2 = pB1[par], b3 = pB1[2 + par];
#pragma unroll
        for (int j = 0; j < 4; ++j) {
            Oa[j] = fmaf(a0, v0[j], Oa[j]); Ob[j] = fmaf(b0, v0[j], Ob[j]);
            Oa[j] = fmaf(a1, v1[j], Oa[j]); Ob[j] = fmaf(b1, v1[j], Ob[j]);
            Oa[j] = fmaf(a2, v2[j], Oa[j]); Ob[j] = fmaf(b2, v2[j], Ob[j]);
            Oa[j] = fmaf(a3, v3[j], Oa[j]); Ob[j] = fmaf(b3, v3[j], Ob[j]);
        }
    }
    // combine even/odd partial sums across the half-waves
#pragma unroll
    for (int j = 0; j < 4; ++j) {
        Oa[j] += __shfl_xor(Oa[j], 32);
        Ob[j] += __shfl_xor(Ob[j], 32);
    }
    // half 0 stores row qa, half 1 stores row qb (each covers all 128 dv)
    if (par == 0) {
        f32x4 o = {Oa[0] * ra, Oa[1] * ra, Oa[2] * ra, Oa[3] * ra};
        *(f32x4*)&out[((size_t)b * NQ + q0 + qa) * NDV + dv0] = o;
    } else {
        f32x4 o = {Ob[0] * rb, Ob[1] * rb, Ob[2] * rb, Ob[3] * rb};
        *(f32x4*)&out[((size_t)b * NQ + q0 + qb) * NDV + dv0] = o;
    }
}

extern "C" void kernel_launch(void* const* d_in, const int* in_sizes, int n_in,
                              void* d_out, int out_size, void* d_ws, size_t ws_size,
                              hipStream_t stream) {
    const float* q  = (const float*)d_in[0];  // (16,128,128) f32
    const float* ks = (const float*)d_in[1];  // (16,512,128) f32
    const float* vs = (const float*)d_in[2];  // (16,512,128) f32
    const int*   vl = (const int*)d_in[3];    // (16,) i32
    const float* wq = (const float*)d_in[4];  // (128,128) f32
    const float* wk = (const float*)d_in[5];  // (128,128) f32
    const float* wv = (const float*)d_in[6];  // (128,) f32

    // ws layout (~9.3 MB)
    float* Eq = (float*)d_ws;                     // 2048*128
    float* Ek = Eq + 2048 * 128;                  // 8192*128
    float* P  = Ek + (size_t)8192 * 128;          // 16*128*512
    float* w2 = P + (size_t)NB * NQ * NK;         // 128
    short* pqh = (short*)(w2 + 128);              // 4 x 16384 bf16 frags
    short* pql = pqh + 16384;
    short* pkh = pql + 16384;
    short* pkl = pkh + 16384;

    wsplit_kernel<<<16, 256, 0, stream>>>(wq, wk, wv, pqh, pql, pkh, pkl, w2);
    proj_kernel<<<640, 256, 0, stream>>>(q, ks, pqh, pql, pkh, pkl, Eq, Ek);
    score_kernel<<<512, 512, 0, stream>>>(Eq, Ek, vl, w2, P);
    av_kernel<<<256, 256, 0, stream>>>(P, vs, vl, (float*)d_out);
}